// Round 2
// baseline (658.878 us; speedup 1.0000x reference)
//
#include <hip/hip_runtime.h>

// (B,H,W) = (16,512,512); bilinear x2 upsample (half-pixel), mask-blend, 1x1 3ch conv, ReLU.
#define BATCH 16
#define HIN   512
#define WIN   512
#define HOUT  1024
#define WOUT  1024

#define OUT_ELEMS   ((size_t)BATCH * 3 * HOUT * WOUT)
#define MASK_ELEMS  ((size_t)BATCH * HOUT * WOUT)

typedef float f32x4 __attribute__((ext_vector_type(4)));

__global__ __launch_bounds__(256) void fused_upsample_conv_kernel(
    const float* __restrict__ mask,   // (16,2,512,512)
    const float* __restrict__ xl,     // (16,3,1024,1024)
    const float* __restrict__ yl,     // (16,3,1024,1024)
    const float* __restrict__ cw,     // (3,3)
    const float* __restrict__ cb,     // (3,)
    float* __restrict__ out)
{
    const int k    = blockIdx.x;        // input row index; block covers output rows 2k, 2k+1
    const int b    = blockIdx.y;
    const int tid  = threadIdx.x;       // 0..255
    const int half = tid >> 7;          // waves 0-1 -> row 2k, waves 2-3 -> row 2k+1
    const int u    = tid & 127;         // covers output cols 8u..8u+7  (input cols 4u-1..4u+4)
    const int oh   = 2 * k + half;

    // vertical bilinear (half-pixel, clamped):
    // even row 2k:  0.25*in[k-1] + 0.75*in[k]
    // odd  row 2k+1: 0.75*in[k] + 0.25*in[k+1]
    int rA, rB; float wA, wB;
    if (half == 0) { rA = (k > 0) ? k - 1 : 0;       rB = k;  wA = 0.25f; wB = 0.75f; }
    else           { rA = k; rB = (k + 1 < HIN) ? k + 1 : HIN - 1; wA = 0.75f; wB = 0.25f; }

    const int c0 = u * 4;                              // aligned float4 col
    const int cm = (c0 > 0) ? c0 - 1 : 0;              // left halo (clamped)
    const int cp = (c0 + 4 < WIN) ? c0 + 4 : WIN - 1;  // right halo (clamped)

    const size_t mplane = (size_t)HIN * WIN;
    const float* mA0 = mask + ((size_t)b * 2 + 0) * mplane + (size_t)rA * WIN;
    const float* mB0 = mask + ((size_t)b * 2 + 0) * mplane + (size_t)rB * WIN;
    const float* mA1 = mask + ((size_t)b * 2 + 1) * mplane + (size_t)rA * WIN;
    const float* mB1 = mask + ((size_t)b * 2 + 1) * mplane + (size_t)rB * WIN;

    // mask loads: aligned float4 + 2 halo scalars per row-pointer (halo hits L1)
    const f32x4 A40 = *(const f32x4*)(mA0 + c0);
    const f32x4 B40 = *(const f32x4*)(mB0 + c0);
    const f32x4 A41 = *(const f32x4*)(mA1 + c0);
    const f32x4 B41 = *(const f32x4*)(mB1 + c0);
    const float Am0 = mA0[cm], Bm0 = mB0[cm], Ap0 = mA0[cp], Bp0 = mB0[cp];
    const float Am1 = mA1[cm], Bm1 = mB1[cm], Ap1 = mA1[cp], Bp1 = mB1[cp];

    // vertical lerp -> 6 values per channel: cols 4u-1, 4u..4u+3, 4u+4
    float vv0[6], vv1[6];
    vv0[0] = wA * Am0 + wB * Bm0;
    vv1[0] = wA * Am1 + wB * Bm1;
#pragma unroll
    for (int j = 0; j < 4; ++j) {
        vv0[j + 1] = wA * A40[j] + wB * B40[j];
        vv1[j + 1] = wA * A41[j] + wB * B41[j];
    }
    vv0[5] = wA * Ap0 + wB * Bp0;
    vv1[5] = wA * Ap1 + wB * Bp1;

    // horizontal lerp -> 8 upsampled mask px per channel
    float xm[8], ym[8];
#pragma unroll
    for (int m = 0; m < 4; ++m) {
        xm[2 * m]     = 0.25f * vv0[m]     + 0.75f * vv0[m + 1];
        xm[2 * m + 1] = 0.75f * vv0[m + 1] + 0.25f * vv0[m + 2];
        ym[2 * m]     = 0.25f * vv1[m]     + 0.75f * vv1[m + 1];
        ym[2 * m + 1] = 0.75f * vv1[m + 1] + 0.25f * vv1[m + 2];
    }

    const size_t oplane = (size_t)HOUT * WOUT;
    const size_t rowoff = (size_t)oh * WOUT + (size_t)u * 8;

    // streamed inputs: nontemporal, 12 float4 loads in flight
    f32x4 X[3][2], Y[3][2];
#pragma unroll
    for (int cc = 0; cc < 3; ++cc) {
        const f32x4* px = (const f32x4*)(xl + ((size_t)b * 3 + cc) * oplane + rowoff);
        const f32x4* py = (const f32x4*)(yl + ((size_t)b * 3 + cc) * oplane + rowoff);
        X[cc][0] = __builtin_nontemporal_load(px);
        X[cc][1] = __builtin_nontemporal_load(px + 1);
        Y[cc][0] = __builtin_nontemporal_load(py);
        Y[cc][1] = __builtin_nontemporal_load(py + 1);
    }

    // fused = xm*xl + ym*yl
    float f[3][8];
#pragma unroll
    for (int cc = 0; cc < 3; ++cc)
#pragma unroll
        for (int j = 0; j < 8; ++j)
            f[cc][j] = xm[j] * X[cc][j >> 2][j & 3] + ym[j] * Y[cc][j >> 2][j & 3];

    const float w0[3] = {cw[0], cw[1], cw[2]};
    const float w1[3] = {cw[3], cw[4], cw[5]};
    const float w2[3] = {cw[6], cw[7], cw[8]};
    const float bb[3] = {cb[0], cb[1], cb[2]};

#pragma unroll
    for (int o = 0; o < 3; ++o) {
        const float* wo = (o == 0) ? w0 : (o == 1) ? w1 : w2;
        f32x4 r0, r1;
#pragma unroll
        for (int j = 0; j < 8; ++j) {
            float v = fmaxf(wo[0] * f[0][j] + wo[1] * f[1][j] + wo[2] * f[2][j] + bb[o], 0.0f);
            if (j < 4) r0[j] = v; else r1[j - 4] = v;
        }
        f32x4* po = (f32x4*)(out + ((size_t)b * 3 + o) * oplane + rowoff);
        __builtin_nontemporal_store(r0, po);
        __builtin_nontemporal_store(r1, po + 1);
    }

    // mask outputs
    f32x4 xa, xb, ya, yb;
#pragma unroll
    for (int j = 0; j < 4; ++j) { xa[j] = xm[j]; xb[j] = xm[j + 4]; ya[j] = ym[j]; yb[j] = ym[j + 4]; }
    f32x4* pxm = (f32x4*)(out + OUT_ELEMS + (size_t)b * oplane + rowoff);
    f32x4* pym = (f32x4*)(out + OUT_ELEMS + MASK_ELEMS + (size_t)b * oplane + rowoff);
    __builtin_nontemporal_store(xa, pxm);
    __builtin_nontemporal_store(xb, pxm + 1);
    __builtin_nontemporal_store(ya, pym);
    __builtin_nontemporal_store(yb, pym + 1);
}

extern "C" void kernel_launch(void* const* d_in, const int* in_sizes, int n_in,
                              void* d_out, int out_size, void* d_ws, size_t ws_size,
                              hipStream_t stream) {
    const float* mask = (const float*)d_in[0];
    const float* xl   = (const float*)d_in[1];
    const float* yl   = (const float*)d_in[2];
    const float* cw   = (const float*)d_in[3];
    const float* cb   = (const float*)d_in[4];
    float* out = (float*)d_out;

    dim3 grid(HIN, BATCH);   // one block per (output row pair, batch)
    dim3 block(256);         // 2 rows x 128 threads x 8 px
    fused_upsample_conv_kernel<<<grid, block, 0, stream>>>(mask, xl, yl, cw, cb, out);
}